// Round 6
// baseline (4516.251 us; speedup 1.0000x reference)
//
#include <hip/hip_runtime.h>
#include <hip/hip_bf16.h>
#include <stdint.h>

// ---------------------------------------------------------------------------
// 2-layer LSTM (B=256, T=1024, H=256). R14: CLUSTER MULTIPLEXING.
//
// R8-R13 evidence: per-step period is a serialized chain of ~5-6 coherent IC
// transactions (~7500cy); compute duty ~15%. Rearranging RTs of one chain
// never helped (R9 +16%, R11 +55%, R13 +11%). R14 amortizes instead:
//  - 128 WGs; WG (g,j) hosts slice j of TWO clusters cA=2g, cB=2g+1.
//    One iteration = 1 step of each cluster: one batched poll, one staging
//    batch, two computes, ONE drain, one fused st64 flag publish.
//  - Flag lines hold BOTH clusters' values: line (g,idx) = {vA, vB} ->
//    poll = 4x dwordx2, publish = 1x st64. Private 128B lines kept.
//  - L1 skewed 2 steps (iter k: L0 step k, L1 step k-2): all cross-layer
//    edges get >=1 full iteration of slack -> first-read poll hits. Guards
//    (flag v = steps completed): L0 polls L0>=k, L1>=k-3 (overwrite h0(k-4),
//    op-reduce col k-4); L1 polls L0>=k-1 (h0(k-2)), L1>=k-2 (h1(k-3)).
//  - op widened to 8 slots: post-publish reduce of col k-4 (slot k&7) is
//    overwritten by L1 col k+4 at its iter k+6, gated on L0>=k+5 => >=3
//    iterations after the reduce. No race.
//  - Compute/layout code byte-identical to R12 (proven): W-permute pack,
//    xpose4 gate exchange, st64 h publish, stage_tile, store->drain->
//    barrier->publish discipline. LDS 152KB (L1: 3 tile bufs + mid-iter
//    reuse of bufA0 for h1(cB) behind a barrier).
// ---------------------------------------------------------------------------

#define TT 1024
#define NC 16

typedef __attribute__((ext_vector_type(8))) short  bfrag;
typedef __attribute__((ext_vector_type(4))) float  ffrag;
typedef __attribute__((ext_vector_type(2))) int    i2v;

__device__ __forceinline__ float sigf(float v){ return 1.f/(1.f+__expf(-v)); }
__device__ __forceinline__ float tanhfast(float v){
    v = fminf(fmaxf(v,-15.f),15.f);
    float e = __expf(2.f*v);
    return (e-1.f)/(e+1.f);
}
__device__ __forceinline__ void st32(uint32_t* p, uint32_t v){
    __hip_atomic_store(p, v, __ATOMIC_RELAXED, __HIP_MEMORY_SCOPE_AGENT);
}
__device__ __forceinline__ void st64(unsigned long long* p, unsigned long long v){
    __hip_atomic_store(p, v, __ATOMIC_RELAXED, __HIP_MEMORY_SCOPE_AGENT);
}
__device__ __forceinline__ void stf(float* p, float v){
    __hip_atomic_store(p, v, __ATOMIC_RELAXED, __HIP_MEMORY_SCOPE_AGENT);
}
__device__ __forceinline__ void drain_vmem(){
    __asm__ volatile("s_waitcnt vmcnt(0)" ::: "memory");
}
// Direct-to-LDS stage of one 16x32 bf16 A-tile from a per-producer 1KB block.
__device__ __forceinline__ void stage_tile(uint32_t* ldsbase, const uint32_t* hblocks,
                                           int kt, int lane){
    const uint32_t* g = hblocks + (kt << 8) + ((lane & 15) << 4) + ((lane >> 4) << 2);
    uint32_t* l = ldsbase + (kt << 8);
    __builtin_amdgcn_global_load_lds(
        (const __attribute__((address_space(1))) uint32_t*)(uintptr_t)g,
        (__attribute__((address_space(3))) uint32_t*)(uint32_t)(uintptr_t)l,
        16, 0, 0x11);
}
// 4x4 transpose across (reg index) x (lane bits 0-1) - R11/R12-proven.
__device__ __forceinline__ void xpose4(ffrag& a, int lane){
    float x0 = (lane&1) ? a[0] : a[1];
    float y0 = __shfl_xor(x0, 1);
    a[0] = (lane&1) ? y0 : a[0];  a[1] = (lane&1) ? a[1] : y0;
    float x1 = (lane&1) ? a[2] : a[3];
    float y1 = __shfl_xor(x1, 1);
    a[2] = (lane&1) ? y1 : a[2];  a[3] = (lane&1) ? a[3] : y1;
    float x2 = (lane&2) ? a[0] : a[2];
    float y2 = __shfl_xor(x2, 2);
    a[0] = (lane&2) ? y2 : a[0];  a[2] = (lane&2) ? a[2] : y2;
    float x3 = (lane&2) ? a[1] : a[3];
    float y3 = __shfl_xor(x3, 2);
    a[1] = (lane&2) ? y3 : a[1];  a[3] = (lane&2) ? a[3] : y3;
}
// Reduce output column `col` for both hosted clusters (coherent op gather).
__device__ __forceinline__ void reduce2(const float* op, int cA, int cB, int col,
                                        int tid, float blin_r, float* __restrict__ out){
    int slot = col & 7;
    const float* oA = op + ((slot * NC + cA) * 32 + (tid & 15)) * 16 + (tid >> 4);
    const float* oB = op + ((slot * NC + cB) * 32 + (tid & 15)) * 16 + (tid >> 4);
    float ra, rb, rc, rd;
    __asm__ volatile(
        "global_load_dword %0, %4, off sc0 sc1\n\t"
        "global_load_dword %1, %5, off sc0 sc1\n\t"
        "global_load_dword %2, %6, off sc0 sc1\n\t"
        "global_load_dword %3, %7, off sc0 sc1\n\t"
        "s_waitcnt vmcnt(0)"
        : "=&v"(ra), "=&v"(rb), "=&v"(rc), "=&v"(rd)
        : "v"(oA), "v"(oA + 256), "v"(oB), "v"(oB + 256) : "memory");
    float vA = ra + rb, vB = rc + rd;
    vA += __shfl_down(vA, 8, 16); vA += __shfl_down(vA, 4, 16);
    vA += __shfl_down(vA, 2, 16); vA += __shfl_down(vA, 1, 16);
    vB += __shfl_down(vB, 8, 16); vB += __shfl_down(vB, 4, 16);
    vB += __shfl_down(vB, 2, 16); vB += __shfl_down(vB, 1, 16);
    if ((tid & 15) == 0) {
        out[(cA * 16 + (tid >> 4)) * TT + col] = vA + blin_r;
        out[(cB * 16 + (tid >> 4)) * TT + col] = vB + blin_r;
    }
}

__global__ void __launch_bounds__(256, 1)
lstm_kernel(const float* __restrict__ x,
            const float* __restrict__ Wih0, const float* __restrict__ Whh0,
            const float* __restrict__ bih0, const float* __restrict__ bhh0,
            const float* __restrict__ Wih1, const float* __restrict__ Whh1,
            const float* __restrict__ bih1, const float* __restrict__ bhh1,
            const float* __restrict__ Wlin, const float* __restrict__ blin,
            float* __restrict__ out, char* __restrict__ ws)
{
    const int tid = threadIdx.x;
    const int wg  = blockIdx.x;          // 0..127
    const int g   = wg >> 4;             // supercluster 0..7
    const int j   = wg & 15;
    const bool isL0 = (j < 8);
    const int  u0   = (isL0 ? j : (j - 8)) * 32;
    const int  cA = g * 2, cB = g * 2 + 1;

    // ws: flag lines 8 superclusters x 16 lines x 128B = 16KB (in 64KB region)
    //     h0: [4 slots][NC][8 prod][16 rows][32 units bf16] = 512KB
    //     h1: 512KB | op: [8 slots][NC][32 partials][16 rows] fp32 = 256KB
    char* flg = ws + (size_t)g * 4096;
    uint32_t* h0w = (uint32_t*)(ws + 65536);
    uint32_t* h1w = h0w + 4 * NC * 8 * 256;
    float*    op  = (float*)(h1w + 4 * NC * 8 * 256);

    // LDS: Wt 64KB | Wt2 64KB (L1) | tA0 8KB | tA1 8KB | tB0 8KB = 152KB
    __shared__ __attribute__((aligned(16))) char S[155648];
    __hip_bfloat16* Wt  = (__hip_bfloat16*)S;            // L0: Whh0; L1: Wih1
    __hip_bfloat16* Wt2 = (__hip_bfloat16*)(S + 65536);  // L1: Whh1
    char* tA0 = S + 131072;
    char* tA1 = S + 139264;
    char* tB0 = S + 147456;

    const int lane = tid & 63, wave = tid >> 6;
    const int q_l  = (lane >> 2) & 3;
    const int g_l  = lane & 3;
    const int rg   = lane >> 4;
    const int row  = rg * 4 + g_l;          // batch row within cluster (0..15)
    const int u_e  = wave * 8 + q_l * 2;    // local unit (even)

    // ---- one-time init (R11/R12-proven W permutation pack; j-dependent only,
    //      shared by both hosted clusters) ----
    {
        const float* Wsrc = isL0 ? Whh0 : Wih1;
        for (int i = tid; i < 128 * 256; i += 256) {
            int n = i >> 8, k = i & 255;
            int ntile = n >> 4, cc = n & 15, q = cc >> 2, gg = cc & 3;
            int unit = 8 * (ntile >> 1) + 2 * q + (ntile & 1);
            int r = gg * 256 + u0 + unit;
            int ln = (n & 15) | (((k >> 3) & 3) << 4);
            int toff = (ntile * 8 + (k >> 5)) * 1024 + ln * 16 + (k & 7) * 2;
            *(__hip_bfloat16*)((char*)Wt + toff) = __float2bfloat16(Wsrc[r * 256 + k]);
            if (!isL0)
                *(__hip_bfloat16*)((char*)Wt2 + toff) = __float2bfloat16(Whh1[r * 256 + k]);
        }
        // zero own h(-1) slot-3 blocks for BOTH clusters (redundant w/ memset)
        uint32_t* zA = isL0 ? (h0w + ((3 * NC + cA) * 8 + j) * 256)
                            : (h1w + ((3 * NC + cA) * 8 + (j - 8)) * 256);
        uint32_t* zB = isL0 ? (h0w + ((3 * NC + cB) * 8 + j) * 256)
                            : (h1w + ((3 * NC + cB) * 8 + (j - 8)) * 256);
        st32(zA + tid, 0u);
        st32(zB + tid, 0u);
    }
    // per-lane constants (regs), j-dependent -> shared across clusters
    float be0,be1,be2,be3, bo0,bo1,bo2,bo3;
    float we0=0,we1=0,we2=0,we3=0, wo0=0,wo1=0,wo2=0,wo3=0;
    float wle=0, wlo=0;
    {
        const float* bi = isL0 ? bih0 : bih1;
        const float* bh = isL0 ? bhh0 : bhh1;
        int r0 = u0 + u_e;
        be0 = bi[r0] + bh[r0];               bo0 = bi[r0+1] + bh[r0+1];
        be1 = bi[256+r0] + bh[256+r0];       bo1 = bi[256+r0+1] + bh[256+r0+1];
        be2 = bi[512+r0] + bh[512+r0];       bo2 = bi[512+r0+1] + bh[512+r0+1];
        be3 = bi[768+r0] + bh[768+r0];       bo3 = bi[768+r0+1] + bh[768+r0+1];
        if (isL0) {
            we0 = Wih0[r0];     wo0 = Wih0[r0+1];
            we1 = Wih0[256+r0]; wo1 = Wih0[256+r0+1];
            we2 = Wih0[512+r0]; wo2 = Wih0[512+r0+1];
            we3 = Wih0[768+r0]; wo3 = Wih0[768+r0+1];
        } else {
            wle = Wlin[u0 + u_e]; wlo = Wlin[u0 + u_e + 1];
        }
    }
    const float blin_r = blin[0];
    drain_vmem();
    __syncthreads();
    if (tid == 0) st64((unsigned long long*)(flg + j * 128), 0ull);

    // flag geometry: line (g, idx) = {vA, vB}; this WG owns line idx=j.
    const i2v* p0 = (const i2v*)(flg + (wave)      * 128);   // L0 set
    const i2v* p1 = (const i2v*)(flg + (wave + 4)  * 128);
    const i2v* p2 = (const i2v*)(flg + (8 + wave)  * 128);   // L1 set
    const i2v* p3 = (const i2v*)(flg + (12 + wave) * 128);
    unsigned long long* myline = (unsigned long long*)(flg + j * 128);

    // Wt bases for this wave's 2 n-tiles
    const char* wb0 = (const char*)Wt + (wave * 2) * 8192 + lane * 16;
    const char* wb1 = wb0 + 8192;
    const char* wc0 = (const char*)Wt2 + (wave * 2) * 8192 + lane * 16;
    const char* wc1 = wc0 + 8192;

    float cAa = 0.f, cAb = 0.f, cBa = 0.f, cBb = 0.f;

    if (isL0) {
        for (int k = 0; k < TT; ++k) {
            // poll: peers' h0(k-1) [L0 >= k]; overwrite+reduce guard [L1 >= k-3]
            {
                i2v v0, v1, v2, v3; int bail = 0;
                for (;;) {
                    __asm__ volatile(
                        "global_load_dwordx2 %0, %4, off sc0 sc1\n\t"
                        "global_load_dwordx2 %1, %5, off sc0 sc1\n\t"
                        "global_load_dwordx2 %2, %6, off sc0 sc1\n\t"
                        "global_load_dwordx2 %3, %7, off sc0 sc1\n\t"
                        "s_waitcnt vmcnt(0)"
                        : "=&v"(v0), "=&v"(v1), "=&v"(v2), "=&v"(v3)
                        : "v"(p0), "v"(p1), "v"(p2), "v"(p3) : "memory");
                    bool ok = (v0.x >= k) && (v0.y >= k) && (v1.x >= k) && (v1.y >= k)
                           && (v2.x >= k-3) && (v2.y >= k-3) && (v3.x >= k-3) && (v3.y >= k-3);
                    if (__all(ok)) break;
                    if (++bail > (1 << 21)) break;    // fail visibly, never hang
                    __builtin_amdgcn_s_sleep(1);
                }
            }
            float xvA = x[(cA * 16 + row) * TT + k];
            float xvB = x[(cB * 16 + row) * TT + k];
            const uint32_t* srcA = h0w + (((k + 3) & 3) * NC + cA) * 8 * 256;
            const uint32_t* srcB = h0w + (((k + 3) & 3) * NC + cB) * 8 * 256;
            stage_tile((uint32_t*)tA0, srcA, wave, lane);
            stage_tile((uint32_t*)tA0, srcA, wave + 4, lane);
            stage_tile((uint32_t*)tB0, srcB, wave, lane);
            stage_tile((uint32_t*)tB0, srcB, wave + 4, lane);
            __syncthreads();

            uint32_t pkA, pkB;
            {   // cluster A
                ffrag a0 = {0.f,0.f,0.f,0.f}, a1 = {0.f,0.f,0.f,0.f};
                #pragma unroll
                for (int kt = 0; kt < 8; ++kt) {
                    bfrag av = *(const bfrag*)(tA0 + kt * 1024 + lane * 16);
                    bfrag b0 = *(const bfrag*)(wb0 + kt * 1024);
                    bfrag b1 = *(const bfrag*)(wb1 + kt * 1024);
                    a0 = __builtin_amdgcn_mfma_f32_16x16x32_bf16(av, b0, a0, 0, 0, 0);
                    a1 = __builtin_amdgcn_mfma_f32_16x16x32_bf16(av, b1, a1, 0, 0, 0);
                }
                xpose4(a0, lane); xpose4(a1, lane);
                float iv = a0[0] + fmaf(xvA, we0, be0);
                float fv = a0[1] + fmaf(xvA, we1, be1);
                float gv = a0[2] + fmaf(xvA, we2, be2);
                float ov = a0[3] + fmaf(xvA, we3, be3);
                cAa = sigf(fv) * cAa + sigf(iv) * tanhfast(gv);
                float hn0 = sigf(ov) * tanhfast(cAa);
                iv = a1[0] + fmaf(xvA, wo0, bo0);
                fv = a1[1] + fmaf(xvA, wo1, bo1);
                gv = a1[2] + fmaf(xvA, wo2, bo2);
                ov = a1[3] + fmaf(xvA, wo3, bo3);
                cAb = sigf(fv) * cAb + sigf(iv) * tanhfast(gv);
                float hn1 = sigf(ov) * tanhfast(cAb);
                __hip_bfloat16 hb0 = __float2bfloat16(hn0), hb1 = __float2bfloat16(hn1);
                pkA = ((uint32_t)(*(uint16_t*)&hb1) << 16) | (uint32_t)(*(uint16_t*)&hb0);
            }
            {   // cluster B
                ffrag a0 = {0.f,0.f,0.f,0.f}, a1 = {0.f,0.f,0.f,0.f};
                #pragma unroll
                for (int kt = 0; kt < 8; ++kt) {
                    bfrag av = *(const bfrag*)(tB0 + kt * 1024 + lane * 16);
                    bfrag b0 = *(const bfrag*)(wb0 + kt * 1024);
                    bfrag b1 = *(const bfrag*)(wb1 + kt * 1024);
                    a0 = __builtin_amdgcn_mfma_f32_16x16x32_bf16(av, b0, a0, 0, 0, 0);
                    a1 = __builtin_amdgcn_mfma_f32_16x16x32_bf16(av, b1, a1, 0, 0, 0);
                }
                xpose4(a0, lane); xpose4(a1, lane);
                float iv = a0[0] + fmaf(xvB, we0, be0);
                float fv = a0[1] + fmaf(xvB, we1, be1);
                float gv = a0[2] + fmaf(xvB, we2, be2);
                float ov = a0[3] + fmaf(xvB, we3, be3);
                cBa = sigf(fv) * cBa + sigf(iv) * tanhfast(gv);
                float hn0 = sigf(ov) * tanhfast(cBa);
                iv = a1[0] + fmaf(xvB, wo0, bo0);
                fv = a1[1] + fmaf(xvB, wo1, bo1);
                gv = a1[2] + fmaf(xvB, wo2, bo2);
                ov = a1[3] + fmaf(xvB, wo3, bo3);
                cBb = sigf(fv) * cBb + sigf(iv) * tanhfast(gv);
                float hn1 = sigf(ov) * tanhfast(cBb);
                __hip_bfloat16 hb0 = __float2bfloat16(hn0), hb1 = __float2bfloat16(hn1);
                pkB = ((uint32_t)(*(uint16_t*)&hb1) << 16) | (uint32_t)(*(uint16_t*)&hb0);
            }
            uint32_t nbA = __shfl_down(pkA, 4);
            uint32_t nbB = __shfl_down(pkB, 4);
            if ((q_l & 1) == 0) {
                st64((unsigned long long*)
                     (h0w + (((k & 3) * NC + cA) * 8 + j) * 256 + row * 16 + wave * 4 + q_l),
                     (unsigned long long)pkA | ((unsigned long long)nbA << 32));
                st64((unsigned long long*)
                     (h0w + (((k & 3) * NC + cB) * 8 + j) * 256 + row * 16 + wave * 4 + q_l),
                     (unsigned long long)pkB | ((unsigned long long)nbB << 32));
            }
            drain_vmem();                    // per-wave: both h slices acked
            __syncthreads();
            if (tid == 0)
                st64(myline, (unsigned long long)(uint32_t)(k + 1) * 0x100000001ull);

            // distributed out-reduce: column k-4 for both clusters (post-
            // publish, off-chain; guard L1 >= k-3 established at poll; slot
            // overwritten only >=3 iterations later - 8-slot op).
            if (k >= 4 && j == ((k - 4) & 7))
                reduce2(op, cA, cB, k - 4, tid, blin_r, out);
        }
        // tail: columns TT-4..TT-1 by j=4..7 (need all L1 flags >= TT)
        if (j >= 4) {
            i2v v2, v3; int bail = 0;
            for (;;) {
                __asm__ volatile(
                    "global_load_dwordx2 %0, %2, off sc0 sc1\n\t"
                    "global_load_dwordx2 %1, %3, off sc0 sc1\n\t"
                    "s_waitcnt vmcnt(0)"
                    : "=&v"(v2), "=&v"(v3) : "v"(p2), "v"(p3) : "memory");
                bool ok = (v2.x >= TT) && (v2.y >= TT) && (v3.x >= TT) && (v3.y >= TT);
                if (__all(ok)) break;
                if (++bail > (1 << 22)) break;
                __builtin_amdgcn_s_sleep(1);
            }
            __syncthreads();
            reduce2(op, cA, cB, TT - 8 + j, tid, blin_r, out);
        }
    } else {
        for (int k = 2; k < TT + 2; ++k) {
            const int s = k - 2;
            // poll: h0(s) [L0 >= k-1]; peers' h1(s-1) [L1 >= k-2]
            {
                i2v v0, v1, v2, v3; int bail = 0;
                for (;;) {
                    __asm__ volatile(
                        "global_load_dwordx2 %0, %4, off sc0 sc1\n\t"
                        "global_load_dwordx2 %1, %5, off sc0 sc1\n\t"
                        "global_load_dwordx2 %2, %6, off sc0 sc1\n\t"
                        "global_load_dwordx2 %3, %7, off sc0 sc1\n\t"
                        "s_waitcnt vmcnt(0)"
                        : "=&v"(v0), "=&v"(v1), "=&v"(v2), "=&v"(v3)
                        : "v"(p0), "v"(p1), "v"(p2), "v"(p3) : "memory");
                    bool ok = (v0.x >= k-1) && (v0.y >= k-1) && (v1.x >= k-1) && (v1.y >= k-1)
                           && (v2.x >= k-2) && (v2.y >= k-2) && (v3.x >= k-2) && (v3.y >= k-2);
                    if (__all(ok)) break;
                    if (++bail > (1 << 21)) break;
                    __builtin_amdgcn_s_sleep(1);
                }
            }
            const uint32_t* sA0 = h0w + ((s & 3) * NC + cA) * 8 * 256;        // h0(s)
            const uint32_t* sA1 = h1w + (((s + 3) & 3) * NC + cA) * 8 * 256;  // h1(s-1)
            const uint32_t* sB0 = h0w + ((s & 3) * NC + cB) * 8 * 256;
            stage_tile((uint32_t*)tA0, sA0, wave, lane);
            stage_tile((uint32_t*)tA0, sA0, wave + 4, lane);
            stage_tile((uint32_t*)tA1, sA1, wave, lane);
            stage_tile((uint32_t*)tA1, sA1, wave + 4, lane);
            stage_tile((uint32_t*)tB0, sB0, wave, lane);
            stage_tile((uint32_t*)tB0, sB0, wave + 4, lane);
            __syncthreads();

            uint32_t pkA, pkB; float pvA, pvB;
            {   // cluster A: h0(s)@Wih1 + h1(s-1)@Whh1
                ffrag a0 = {0.f,0.f,0.f,0.f}, a1 = {0.f,0.f,0.f,0.f};
                #pragma unroll
                for (int kt = 0; kt < 8; ++kt) {
                    bfrag av = *(const bfrag*)(tA0 + kt * 1024 + lane * 16);
                    bfrag b0 = *(const bfrag*)(wb0 + kt * 1024);
                    bfrag b1 = *(const bfrag*)(wb1 + kt * 1024);
                    a0 = __builtin_amdgcn_mfma_f32_16x16x32_bf16(av, b0, a0, 0, 0, 0);
                    a1 = __builtin_amdgcn_mfma_f32_16x16x32_bf16(av, b1, a1, 0, 0, 0);
                }
                #pragma unroll
                for (int kt = 0; kt < 8; ++kt) {
                    bfrag av = *(const bfrag*)(tA1 + kt * 1024 + lane * 16);
                    bfrag b0 = *(const bfrag*)(wc0 + kt * 1024);
                    bfrag b1 = *(const bfrag*)(wc1 + kt * 1024);
                    a0 = __builtin_amdgcn_mfma_f32_16x16x32_bf16(av, b0, a0, 0, 0, 0);
                    a1 = __builtin_amdgcn_mfma_f32_16x16x32_bf16(av, b1, a1, 0, 0, 0);
                }
                xpose4(a0, lane); xpose4(a1, lane);
                float iv = a0[0] + be0, fv = a0[1] + be1;
                float gv = a0[2] + be2, ov = a0[3] + be3;
                cAa = sigf(fv) * cAa + sigf(iv) * tanhfast(gv);
                float hn0 = sigf(ov) * tanhfast(cAa);
                iv = a1[0] + bo0; fv = a1[1] + bo1;
                gv = a1[2] + bo2; ov = a1[3] + bo3;
                cAb = sigf(fv) * cAb + sigf(iv) * tanhfast(gv);
                float hn1 = sigf(ov) * tanhfast(cAb);
                __hip_bfloat16 hb0 = __float2bfloat16(hn0), hb1 = __float2bfloat16(hn1);
                pkA = ((uint32_t)(*(uint16_t*)&hb1) << 16) | (uint32_t)(*(uint16_t*)&hb0);
                pvA = hn0 * wle + hn1 * wlo;
                pvA += __shfl_xor(pvA, 4);
                pvA += __shfl_xor(pvA, 8);
            }
            __syncthreads();                  // all waves done reading tA0/tA1
            const uint32_t* sB1 = h1w + (((s + 3) & 3) * NC + cB) * 8 * 256;  // h1(s-1) of cB
            stage_tile((uint32_t*)tA0, sB1, wave, lane);      // reuse bufA0
            stage_tile((uint32_t*)tA0, sB1, wave + 4, lane);
            {   // cluster B
                ffrag a0 = {0.f,0.f,0.f,0.f}, a1 = {0.f,0.f,0.f,0.f};
                #pragma unroll
                for (int kt = 0; kt < 8; ++kt) {              // h0(s)@Wih1 (overlaps stage)
                    bfrag av = *(const bfrag*)(tB0 + kt * 1024 + lane * 16);
                    bfrag b0 = *(const bfrag*)(wb0 + kt * 1024);
                    bfrag b1 = *(const bfrag*)(wb1 + kt * 1024);
                    a0 = __builtin_amdgcn_mfma_f32_16x16x32_bf16(av, b0, a0, 0, 0, 0);
                    a1 = __builtin_amdgcn_mfma_f32_16x16x32_bf16(av, b1, a1, 0, 0, 0);
                }
                __syncthreads();              // drains h1B stage (vmcnt(0)+bar)
                #pragma unroll
                for (int kt = 0; kt < 8; ++kt) {              // += h1(s-1)@Whh1
                    bfrag av = *(const bfrag*)(tA0 + kt * 1024 + lane * 16);
                    bfrag b0 = *(const bfrag*)(wc0 + kt * 1024);
                    bfrag b1 = *(const bfrag*)(wc1 + kt * 1024);
                    a0 = __builtin_amdgcn_mfma_f32_16x16x32_bf16(av, b0, a0, 0, 0, 0);
                    a1 = __builtin_amdgcn_mfma_f32_16x16x32_bf16(av, b1, a1, 0, 0, 0);
                }
                xpose4(a0, lane); xpose4(a1, lane);
                float iv = a0[0] + be0, fv = a0[1] + be1;
                float gv = a0[2] + be2, ov = a0[3] + be3;
                cBa = sigf(fv) * cBa + sigf(iv) * tanhfast(gv);
                float hn0 = sigf(ov) * tanhfast(cBa);
                iv = a1[0] + bo0; fv = a1[1] + bo1;
                gv = a1[2] + bo2; ov = a1[3] + bo3;
                cBb = sigf(fv) * cBb + sigf(iv) * tanhfast(gv);
                float hn1 = sigf(ov) * tanhfast(cBb);
                __hip_bfloat16 hb0 = __float2bfloat16(hn0), hb1 = __float2bfloat16(hn1);
                pkB = ((uint32_t)(*(uint16_t*)&hb1) << 16) | (uint32_t)(*(uint16_t*)&hb0);
                pvB = hn0 * wle + hn1 * wlo;
                pvB += __shfl_xor(pvB, 4);
                pvB += __shfl_xor(pvB, 8);
            }
            uint32_t nbA = __shfl_down(pkA, 4);
            uint32_t nbB = __shfl_down(pkB, 4);
            if ((q_l & 1) == 0) {
                st64((unsigned long long*)
                     (h1w + (((s & 3) * NC + cA) * 8 + (j - 8)) * 256 + row * 16 + wave * 4 + q_l),
                     (unsigned long long)pkA | ((unsigned long long)nbA << 32));
                st64((unsigned long long*)
                     (h1w + (((s & 3) * NC + cB) * 8 + (j - 8)) * 256 + row * 16 + wave * 4 + q_l),
                     (unsigned long long)pkB | ((unsigned long long)nbB << 32));
            }
            if ((lane & 12) == 0) {
                stf(op + (((s & 7) * NC + cA) * 32 + (j - 8) * 4 + wave) * 16 + row, pvA);
                stf(op + (((s & 7) * NC + cB) * 32 + (j - 8) * 4 + wave) * 16 + row, pvB);
            }
            drain_vmem();                     // per-wave: h + op acked
            __syncthreads();
            if (tid == 0)
                st64(myline, (unsigned long long)(uint32_t)(k - 1) * 0x100000001ull);
        }
    }
}

extern "C" void kernel_launch(void* const* d_in, const int* in_sizes, int n_in,
                              void* d_out, int out_size, void* d_ws, size_t ws_size,
                              hipStream_t stream)
{
    const float* x    = (const float*)d_in[0];
    const float* Wih0 = (const float*)d_in[1];
    const float* Whh0 = (const float*)d_in[2];
    const float* bih0 = (const float*)d_in[3];
    const float* bhh0 = (const float*)d_in[4];
    const float* Wih1 = (const float*)d_in[5];
    const float* Whh1 = (const float*)d_in[6];
    const float* bih1 = (const float*)d_in[7];
    const float* bhh1 = (const float*)d_in[8];
    const float* Wlin = (const float*)d_in[9];
    const float* blin = (const float*)d_in[10];
    float* out = (float*)d_out;
    char* ws   = (char*)d_ws;

    // 128 blocks x 256 threads, 1 block/CU -> all co-resident (spin-safe).
    lstm_kernel<<<dim3(128), dim3(256), 0, stream>>>(
        x, Wih0, Whh0, bih0, bhh0, Wih1, Whh1, bih1, bhh1, Wlin, blin, out, ws);
}

// Round 7
// 3486.172 us; speedup vs baseline: 1.2955x; 1.2955x over previous
//
#include <hip/hip_runtime.h>
#include <hip/hip_bf16.h>
#include <stdint.h>

// ---------------------------------------------------------------------------
// 2-layer LSTM (B=256, T=1024, H=256). R15: DRAIN-FREE TAGGED PUBLISH.
//
// R8-R14 synthesis: wall = per-step critical-cycle period x 1024; period =
// ~3.5 serialized coherent RTs (RT_coh ~1700-2000cy) + compute. R15 removes
// the producer drain AND the flag-visibility hop from the chain:
//  - h published as 8B atomic chunks {2xbf16, step-tag}; consumer's batched
//    tagged read IS detect+fetch (retry on stale tag, 1-RT quantum).
//    Producer: compute -> issue stores -> done. No vmcnt drain, no
//    post-drain flag.
//  - flags now mean "completed FETCH of iter v-1" (published right after
//    validate, before MFMA). Only used for overwrite/backpressure guards,
//    all with >=2 iterations of slack -> always fast-path. Checked in the
//    same batched load as the data (no extra RT).
//  - raw s_barrier (asm) instead of __syncthreads: compiler emits no
//    vmcnt(0) drain at barriers. 2 barriers/iter: ds_write->reads (with
//    lgkmcnt(0)) and reads->next-iter-writes.
//  - op tagged {f32, col+1}: reducer validates tags, needs no drained flag.
//    Octave reduce: every 8 steps (t%8==4) ALL 8 L0 WGs reduce 8 columns
//    x 2 rows each; op loads issued pre-MFMA, bound by counted vmcnt(1)
//    after the h-store -> ~free. Kills R12's rotating reducer straggler.
//  - Compute path byte-identical to R12 (proven): W-permute pack, xpose4,
//    16x16x32 MFMA, gates. All retry loops have bailouts (fail visibly).
// ---------------------------------------------------------------------------

#define TT 1024
#define NC 16

typedef __attribute__((ext_vector_type(8))) short  bfrag;
typedef __attribute__((ext_vector_type(4))) float  ffrag;
typedef __attribute__((ext_vector_type(4))) int    ifrag;

__device__ __forceinline__ float sigf(float v){ return 1.f/(1.f+__expf(-v)); }
__device__ __forceinline__ float tanhfast(float v){
    v = fminf(fmaxf(v,-15.f),15.f);
    float e = __expf(2.f*v);
    return (e-1.f)/(e+1.f);
}
__device__ __forceinline__ void st32(uint32_t* p, uint32_t v){
    __hip_atomic_store(p, v, __ATOMIC_RELAXED, __HIP_MEMORY_SCOPE_AGENT);
}
__device__ __forceinline__ void st64(unsigned long long* p, unsigned long long v){
    __hip_atomic_store(p, v, __ATOMIC_RELAXED, __HIP_MEMORY_SCOPE_AGENT);
}
__device__ __forceinline__ void drain_vmem(){
    __asm__ volatile("s_waitcnt vmcnt(0)" ::: "memory");
}
__device__ __forceinline__ void barrier_raw(){
    __asm__ volatile("s_barrier" ::: "memory");
}
// 4x4 transpose across (reg index) x (lane bits 0-1) - R11/R12-proven.
__device__ __forceinline__ void xpose4(ffrag& a, int lane){
    float x0 = (lane&1) ? a[0] : a[1];
    float y0 = __shfl_xor(x0, 1);
    a[0] = (lane&1) ? y0 : a[0];  a[1] = (lane&1) ? a[1] : y0;
    float x1 = (lane&1) ? a[2] : a[3];
    float y1 = __shfl_xor(x1, 1);
    a[2] = (lane&1) ? y1 : a[2];  a[3] = (lane&1) ? a[3] : y1;
    float x2 = (lane&2) ? a[0] : a[2];
    float y2 = __shfl_xor(x2, 2);
    a[0] = (lane&2) ? y2 : a[0];  a[2] = (lane&2) ? a[2] : y2;
    float x3 = (lane&2) ? a[1] : a[3];
    float y3 = __shfl_xor(x3, 2);
    a[1] = (lane&2) ? y3 : a[1];  a[3] = (lane&2) ? a[3] : y3;
}

__global__ void __launch_bounds__(256, 1)
lstm_kernel(const float* __restrict__ x,
            const float* __restrict__ Wih0, const float* __restrict__ Whh0,
            const float* __restrict__ bih0, const float* __restrict__ bhh0,
            const float* __restrict__ Wih1, const float* __restrict__ Whh1,
            const float* __restrict__ bih1, const float* __restrict__ bhh1,
            const float* __restrict__ Wlin, const float* __restrict__ blin,
            float* __restrict__ out, char* __restrict__ ws)
{
    const int tid = threadIdx.x;
    const int wg  = blockIdx.x;
    const int c   = wg >> 4;
    const int j   = wg & 15;
    const bool isL0 = (j < 8);
    const int  u0   = (isL0 ? j : (j - 8)) * 32;

    // ws: flags 16c x 16 lines x 128B = 64KB
    //     h0 tagged [4 slots][NC][8 prod][16 rows][16 chunks x 8B] = 1MB
    //     h1 tagged 1MB
    //     op tagged [16 slots][NC][16 rows][32 partials] x 8B = 1MB
    char* flagbase = ws + (size_t)c * 4096;
    char* h0t = ws + 65536;
    char* h1t = h0t + (size_t)4 * NC * 8 * 2048;
    unsigned long long* op =
        (unsigned long long*)(h1t + (size_t)4 * NC * 8 * 2048);

    // LDS: Wt 64KB | Wt2/xs 64KB (aliased) | hs0 8KB | hs1 8KB
    __shared__ __attribute__((aligned(16))) char S[147456];
    __hip_bfloat16* Wt  = (__hip_bfloat16*)S;            // L0: Whh0; L1: Wih1
    __hip_bfloat16* Wt2 = (__hip_bfloat16*)(S + 65536);  // L1: Whh1
    float*          xs  = (float*)(S + 65536);           // L0: x fp32 [t][16]
    char*           hs0 = S + 131072;
    char*           hs1 = S + 139264;

    const int lane = tid & 63, wave = tid >> 6;
    const int q_l  = (lane >> 2) & 3;
    const int g_l  = lane & 3;
    const int rg   = lane >> 4;
    const int row  = rg * 4 + g_l;          // batch row within cluster (0..15)
    const int u_e  = wave * 8 + q_l * 2;    // local unit (even)

    // ---- one-time init (R11/R12-proven W permutation pack) ----
    {
        const float* Wsrc = isL0 ? Whh0 : Wih1;
        for (int i = tid; i < 128 * 256; i += 256) {
            int n = i >> 8, k = i & 255;
            int ntile = n >> 4, cc = n & 15, q = cc >> 2, g = cc & 3;
            int unit = 8 * (ntile >> 1) + 2 * q + (ntile & 1);
            int r = g * 256 + u0 + unit;
            int ln = (n & 15) | (((k >> 3) & 3) << 4);
            int toff = (ntile * 8 + (k >> 5)) * 1024 + ln * 16 + (k & 7) * 2;
            *(__hip_bfloat16*)((char*)Wt + toff) = __float2bfloat16(Wsrc[r * 256 + k]);
            if (!isL0)
                *(__hip_bfloat16*)((char*)Wt2 + toff) = __float2bfloat16(Whh1[r * 256 + k]);
        }
        if (isL0) {
            for (int i = tid; i < 16 * 1024; i += 256)   // xs[t][16 rows]
                xs[i] = x[(c * 16 + (i & 15)) * TT + (i >> 4)];
        }
        // zero own slot-3 tagged block (data 0, tag 0 == "h(-1), tag 0") —
        // REQUIRED: t=0 consumers expect tag 0; stale cross-run tags differ.
        char* z = (isL0 ? h0t : h1t) +
                  (size_t)((3 * NC + c) * 8 + (isL0 ? j : (j - 8))) * 2048;
        st64((unsigned long long*)z + tid, 0ull);
    }
    // per-lane constants (regs)
    float be0,be1,be2,be3, bo0,bo1,bo2,bo3;
    float we0=0,we1=0,we2=0,we3=0, wo0=0,wo1=0,wo2=0,wo3=0;
    float wle=0, wlo=0;
    {
        const float* bi = isL0 ? bih0 : bih1;
        const float* bh = isL0 ? bhh0 : bhh1;
        int r0 = u0 + u_e;
        be0 = bi[r0] + bh[r0];               bo0 = bi[r0+1] + bh[r0+1];
        be1 = bi[256+r0] + bh[256+r0];       bo1 = bi[256+r0+1] + bh[256+r0+1];
        be2 = bi[512+r0] + bh[512+r0];       bo2 = bi[512+r0+1] + bh[512+r0+1];
        be3 = bi[768+r0] + bh[768+r0];       bo3 = bi[768+r0+1] + bh[768+r0+1];
        if (isL0) {
            we0 = Wih0[r0];     wo0 = Wih0[r0+1];
            we1 = Wih0[256+r0]; wo1 = Wih0[256+r0+1];
            we2 = Wih0[512+r0]; wo2 = Wih0[512+r0+1];
            we3 = Wih0[768+r0]; wo3 = Wih0[768+r0+1];
        } else {
            wle = Wlin[u0 + u_e]; wlo = Wlin[u0 + u_e + 1];
        }
    }
    const float blin_r = blin[0];
    drain_vmem();
    __syncthreads();
    if (tid == 0) st32((uint32_t*)(flagbase + j * 128), 0u);

    // flag lines (128B private): line i dword 0 = WG i's flag
    int* fb = (int*)flagbase;
    const int* fL0a = fb + (wave)      * 32;
    const int* fL0b = fb + (wave + 4)  * 32;
    const int* fL1a = fb + (8 + wave)  * 32;
    const int* fL1b = fb + (12 + wave) * 32;
    uint32_t* myflag = (uint32_t*)(fb + j * 32);

    // W bases for this wave's 2 n-tiles
    const char* wb0 = (const char*)Wt + (wave * 2) * 8192 + lane * 16;
    const char* wb1 = wb0 + 8192;
    const char* wc0 = (const char*)Wt2 + (wave * 2) * 8192 + lane * 16;
    const char* wc1 = wc0 + 8192;
    // per-lane offset in a tagged 2KB block: row=(lane&15) stride 128B,
    // chunks (lane>>4)*4..+3 -> 32B
    const int lnt = (lane & 15) * 128 + (lane >> 4) * 32;

    float c0a = 0.f, c0b = 0.f;

    if (isL0) {
        for (int t = 0; t < TT; ++t) {
            // ---- detect+fetch h0(t-1): tags == t; guards: L0>=t-2, L1>=t-3
            const char* blk = h0t + (size_t)((((t + 3) & 3) * NC + c) * 8) * 2048;
            const char* pA = blk + wave * 2048 + lnt;
            const char* pB = blk + (wave + 4) * 2048 + lnt;
            ifrag r0, r1, r2, r3; int f0, f1, f2, f3;
            int bail = 0;
            for (;;) {
                __asm__ volatile(
                    "global_load_dwordx4 %0, %8, off sc0 sc1\n\t"
                    "global_load_dwordx4 %1, %8, off offset:16 sc0 sc1\n\t"
                    "global_load_dwordx4 %2, %9, off sc0 sc1\n\t"
                    "global_load_dwordx4 %3, %9, off offset:16 sc0 sc1\n\t"
                    "global_load_dword %4, %10, off sc0 sc1\n\t"
                    "global_load_dword %5, %11, off sc0 sc1\n\t"
                    "global_load_dword %6, %12, off sc0 sc1\n\t"
                    "global_load_dword %7, %13, off sc0 sc1\n\t"
                    "s_waitcnt vmcnt(0)"
                    : "=&v"(r0), "=&v"(r1), "=&v"(r2), "=&v"(r3),
                      "=&v"(f0), "=&v"(f1), "=&v"(f2), "=&v"(f3)
                    : "v"(pA), "v"(pB), "v"(fL0a), "v"(fL0b), "v"(fL1a), "v"(fL1b)
                    : "memory");
                bool ok = (r0.y==t) & (r0.w==t) & (r1.y==t) & (r1.w==t)
                        & (r2.y==t) & (r2.w==t) & (r3.y==t) & (r3.w==t)
                        & (f0>=t-2) & (f1>=t-2) & (f2>=t-3) & (f3>=t-3);
                if (__all(ok)) break;
                if (++bail > (1 << 21)) break;       // fail visibly, no hang
                if (bail > 1) __builtin_amdgcn_s_sleep(1);
            }
            *(ifrag*)(hs0 + wave * 1024 + lane * 16)       = (ifrag){r0.x, r0.z, r1.x, r1.z};
            *(ifrag*)(hs0 + (wave + 4) * 1024 + lane * 16) = (ifrag){r2.x, r2.z, r3.x, r3.z};
            __asm__ volatile("s_waitcnt lgkmcnt(0)" ::: "memory");
            barrier_raw();                            // writes -> reads
            if (tid == 0) st32(myflag, (uint32_t)(t + 1));  // fetch-complete

            // octave reduce: at t%8==4, cols t-12..t-5, this WG rows 2j,2j+1.
            // op loads issued NOW, bound after the h-store (counted vmcnt).
            const bool red = (t >= 12) && ((t & 7) == 4);
            ifrag o0, o1, o2, o3;
            int rrow = 0, col = 0;
            const char* ob = nullptr;
            if (red) {
                rrow = 2 * j + (lane >> 5);
                col  = (t - 12) + ((lane >> 2) & 7);
                int slot = col & 15, p0 = (lane & 3) * 8;
                ob = (const char*)(op + (size_t)((slot * NC + c) * 16 + rrow) * 32 + p0);
                __asm__ volatile(
                    "global_load_dwordx4 %0, %4, off sc0 sc1\n\t"
                    "global_load_dwordx4 %1, %4, off offset:16 sc0 sc1\n\t"
                    "global_load_dwordx4 %2, %4, off offset:32 sc0 sc1\n\t"
                    "global_load_dwordx4 %3, %4, off offset:48 sc0 sc1"
                    : "=&v"(o0), "=&v"(o1), "=&v"(o2), "=&v"(o3)
                    : "v"(ob) : "memory");
            }

            ffrag a0 = {0.f,0.f,0.f,0.f}, a1 = {0.f,0.f,0.f,0.f};
            #pragma unroll
            for (int kt = 0; kt < 8; ++kt) {
                bfrag av = *(const bfrag*)(hs0 + kt * 1024 + lane * 16);
                bfrag b0 = *(const bfrag*)(wb0 + kt * 1024);
                bfrag b1 = *(const bfrag*)(wb1 + kt * 1024);
                a0 = __builtin_amdgcn_mfma_f32_16x16x32_bf16(av, b0, a0, 0, 0, 0);
                a1 = __builtin_amdgcn_mfma_f32_16x16x32_bf16(av, b1, a1, 0, 0, 0);
            }
            xpose4(a0, lane);
            xpose4(a1, lane);

            float xv = xs[t * 16 + row];
            float iv = a0[0] + fmaf(xv, we0, be0);
            float fv = a0[1] + fmaf(xv, we1, be1);
            float gv = a0[2] + fmaf(xv, we2, be2);
            float ov = a0[3] + fmaf(xv, we3, be3);
            c0a = sigf(fv) * c0a + sigf(iv) * tanhfast(gv);
            float hn0 = sigf(ov) * tanhfast(c0a);
            iv = a1[0] + fmaf(xv, wo0, bo0);
            fv = a1[1] + fmaf(xv, wo1, bo1);
            gv = a1[2] + fmaf(xv, wo2, bo2);
            ov = a1[3] + fmaf(xv, wo3, bo3);
            c0b = sigf(fv) * c0b + sigf(iv) * tanhfast(gv);
            float hn1 = sigf(ov) * tanhfast(c0b);

            __hip_bfloat16 hb0 = __float2bfloat16(hn0), hb1 = __float2bfloat16(hn1);
            uint32_t pk = ((uint32_t)(*(uint16_t*)&hb1) << 16) | (uint32_t)(*(uint16_t*)&hb0);
            // publish h0(t): one tagged 8B chunk per lane. NO drain.
            st64((unsigned long long*)
                 (h0t + (size_t)(((t & 3) * NC + c) * 8 + j) * 2048
                      + row * 128 + (wave * 4 + q_l) * 8),
                 (unsigned long long)pk | ((unsigned long long)(uint32_t)(t + 1) << 32));

            if (red) {
                // wait op loads only (oldest); h-store stays in flight
                __asm__ volatile("s_waitcnt vmcnt(1)"
                                 : "+v"(o0), "+v"(o1), "+v"(o2), "+v"(o3) :: "memory");
                __builtin_amdgcn_sched_barrier(0);
                int tgt = col + 1, bail2 = 0;
                while (!__all((o0.y==tgt)&(o0.w==tgt)&(o1.y==tgt)&(o1.w==tgt)
                            & (o2.y==tgt)&(o2.w==tgt)&(o3.y==tgt)&(o3.w==tgt))) {
                    if (++bail2 > (1 << 21)) break;
                    __builtin_amdgcn_s_sleep(1);
                    __asm__ volatile(
                        "global_load_dwordx4 %0, %4, off sc0 sc1\n\t"
                        "global_load_dwordx4 %1, %4, off offset:16 sc0 sc1\n\t"
                        "global_load_dwordx4 %2, %4, off offset:32 sc0 sc1\n\t"
                        "global_load_dwordx4 %3, %4, off offset:48 sc0 sc1\n\t"
                        "s_waitcnt vmcnt(0)"
                        : "=&v"(o0), "=&v"(o1), "=&v"(o2), "=&v"(o3)
                        : "v"(ob) : "memory");
                }
                float v = __int_as_float(o0.x) + __int_as_float(o0.z)
                        + __int_as_float(o1.x) + __int_as_float(o1.z)
                        + __int_as_float(o2.x) + __int_as_float(o2.z)
                        + __int_as_float(o3.x) + __int_as_float(o3.z);
                v += __shfl_xor(v, 1);
                v += __shfl_xor(v, 2);
                if ((lane & 3) == 0) out[(c * 16 + rrow) * TT + col] = v + blin_r;
            }
            barrier_raw();                            // reads -> next writes
        }
        // ---- tail: cols TT-8..TT-1, all L0 WGs (rows 2j,2j+1) ----
        {
            int f2, f3, bail = 0;
            for (;;) {
                __asm__ volatile(
                    "global_load_dword %0, %2, off sc0 sc1\n\t"
                    "global_load_dword %1, %3, off sc0 sc1\n\t"
                    "s_waitcnt vmcnt(0)"
                    : "=&v"(f2), "=&v"(f3) : "v"(fL1a), "v"(fL1b) : "memory");
                if (__all((f2 >= TT + 1) && (f3 >= TT + 1))) break;
                if (++bail > (1 << 22)) break;
                __builtin_amdgcn_s_sleep(1);
            }
            barrier_raw();
            int rrow = 2 * j + (lane >> 5);
            int col  = (TT - 8) + ((lane >> 2) & 7);
            int slot = col & 15, p0 = (lane & 3) * 8;
            const char* ob = (const char*)(op + (size_t)((slot * NC + c) * 16 + rrow) * 32 + p0);
            ifrag o0, o1, o2, o3; int tgt = col + 1, bail2 = 0;
            for (;;) {
                __asm__ volatile(
                    "global_load_dwordx4 %0, %4, off sc0 sc1\n\t"
                    "global_load_dwordx4 %1, %4, off offset:16 sc0 sc1\n\t"
                    "global_load_dwordx4 %2, %4, off offset:32 sc0 sc1\n\t"
                    "global_load_dwordx4 %3, %4, off offset:48 sc0 sc1\n\t"
                    "s_waitcnt vmcnt(0)"
                    : "=&v"(o0), "=&v"(o1), "=&v"(o2), "=&v"(o3)
                    : "v"(ob) : "memory");
                if (__all((o0.y==tgt)&(o0.w==tgt)&(o1.y==tgt)&(o1.w==tgt)
                        & (o2.y==tgt)&(o2.w==tgt)&(o3.y==tgt)&(o3.w==tgt))) break;
                if (++bail2 > (1 << 21)) break;
                __builtin_amdgcn_s_sleep(1);
            }
            float v = __int_as_float(o0.x) + __int_as_float(o0.z)
                    + __int_as_float(o1.x) + __int_as_float(o1.z)
                    + __int_as_float(o2.x) + __int_as_float(o2.z)
                    + __int_as_float(o3.x) + __int_as_float(o3.z);
            v += __shfl_xor(v, 1);
            v += __shfl_xor(v, 2);
            if ((lane & 3) == 0) out[(c * 16 + rrow) * TT + col] = v + blin_r;
        }
    } else {
        for (int s = 0; s < TT; ++s) {
            // ---- detect+fetch h0(s) [tags s+1] + h1(s-1) [tags s];
            //      guards: L0>=s-2 (op overwrite), L1>=s-2 (h1 overwrite)
            const char* b0p = h0t + (size_t)(((s & 3) * NC + c) * 8) * 2048;
            const char* pA0 = b0p + wave * 2048 + lnt;
            const char* pB0 = b0p + (wave + 4) * 2048 + lnt;
            const char* b1p = h1t + (size_t)((((s + 3) & 3) * NC + c) * 8) * 2048;
            const char* pA1 = b1p + wave * 2048 + lnt;
            const char* pB1 = b1p + (wave + 4) * 2048 + lnt;
            ifrag r0, r1, r2, r3, r4, r5, r6, r7; int f0, f1, f2, f3;
            int bail = 0;
            for (;;) {
                __asm__ volatile(
                    "global_load_dwordx4 %0,  %12, off sc0 sc1\n\t"
                    "global_load_dwordx4 %1,  %12, off offset:16 sc0 sc1\n\t"
                    "global_load_dwordx4 %2,  %13, off sc0 sc1\n\t"
                    "global_load_dwordx4 %3,  %13, off offset:16 sc0 sc1\n\t"
                    "global_load_dwordx4 %4,  %14, off sc0 sc1\n\t"
                    "global_load_dwordx4 %5,  %14, off offset:16 sc0 sc1\n\t"
                    "global_load_dwordx4 %6,  %15, off sc0 sc1\n\t"
                    "global_load_dwordx4 %7,  %15, off offset:16 sc0 sc1\n\t"
                    "global_load_dword %8,  %16, off sc0 sc1\n\t"
                    "global_load_dword %9,  %17, off sc0 sc1\n\t"
                    "global_load_dword %10, %18, off sc0 sc1\n\t"
                    "global_load_dword %11, %19, off sc0 sc1\n\t"
                    "s_waitcnt vmcnt(0)"
                    : "=&v"(r0), "=&v"(r1), "=&v"(r2), "=&v"(r3),
                      "=&v"(r4), "=&v"(r5), "=&v"(r6), "=&v"(r7),
                      "=&v"(f0), "=&v"(f1), "=&v"(f2), "=&v"(f3)
                    : "v"(pA0), "v"(pB0), "v"(pA1), "v"(pB1),
                      "v"(fL0a), "v"(fL0b), "v"(fL1a), "v"(fL1b)
                    : "memory");
                int e0 = s + 1, e1 = s;
                bool ok = (r0.y==e0)&(r0.w==e0)&(r1.y==e0)&(r1.w==e0)
                        & (r2.y==e0)&(r2.w==e0)&(r3.y==e0)&(r3.w==e0)
                        & (r4.y==e1)&(r4.w==e1)&(r5.y==e1)&(r5.w==e1)
                        & (r6.y==e1)&(r6.w==e1)&(r7.y==e1)&(r7.w==e1)
                        & (f0>=s-2)&(f1>=s-2)&(f2>=s-2)&(f3>=s-2);
                if (__all(ok)) break;
                if (++bail > (1 << 21)) break;
                if (bail > 1) __builtin_amdgcn_s_sleep(1);
            }
            *(ifrag*)(hs0 + wave * 1024 + lane * 16)       = (ifrag){r0.x, r0.z, r1.x, r1.z};
            *(ifrag*)(hs0 + (wave + 4) * 1024 + lane * 16) = (ifrag){r2.x, r2.z, r3.x, r3.z};
            *(ifrag*)(hs1 + wave * 1024 + lane * 16)       = (ifrag){r4.x, r4.z, r5.x, r5.z};
            *(ifrag*)(hs1 + (wave + 4) * 1024 + lane * 16) = (ifrag){r6.x, r6.z, r7.x, r7.z};
            __asm__ volatile("s_waitcnt lgkmcnt(0)" ::: "memory");
            barrier_raw();
            if (tid == 0) st32(myflag, (uint32_t)(s + 1));

            ffrag a0 = {0.f,0.f,0.f,0.f}, a1 = {0.f,0.f,0.f,0.f};
            #pragma unroll
            for (int kt = 0; kt < 8; ++kt) {       // h0(s) @ Wih1
                bfrag av = *(const bfrag*)(hs0 + kt * 1024 + lane * 16);
                bfrag b0 = *(const bfrag*)(wb0 + kt * 1024);
                bfrag b1 = *(const bfrag*)(wb1 + kt * 1024);
                a0 = __builtin_amdgcn_mfma_f32_16x16x32_bf16(av, b0, a0, 0, 0, 0);
                a1 = __builtin_amdgcn_mfma_f32_16x16x32_bf16(av, b1, a1, 0, 0, 0);
            }
            #pragma unroll
            for (int kt = 0; kt < 8; ++kt) {       // += h1(s-1) @ Whh1
                bfrag av = *(const bfrag*)(hs1 + kt * 1024 + lane * 16);
                bfrag b0 = *(const bfrag*)(wc0 + kt * 1024);
                bfrag b1 = *(const bfrag*)(wc1 + kt * 1024);
                a0 = __builtin_amdgcn_mfma_f32_16x16x32_bf16(av, b0, a0, 0, 0, 0);
                a1 = __builtin_amdgcn_mfma_f32_16x16x32_bf16(av, b1, a1, 0, 0, 0);
            }
            xpose4(a0, lane);
            xpose4(a1, lane);

            float iv = a0[0] + be0, fv = a0[1] + be1;
            float gv = a0[2] + be2, ov = a0[3] + be3;
            c0a = sigf(fv) * c0a + sigf(iv) * tanhfast(gv);
            float hn0 = sigf(ov) * tanhfast(c0a);
            iv = a1[0] + bo0; fv = a1[1] + bo1;
            gv = a1[2] + bo2; ov = a1[3] + bo3;
            c0b = sigf(fv) * c0b + sigf(iv) * tanhfast(gv);
            float hn1 = sigf(ov) * tanhfast(c0b);

            __hip_bfloat16 hb0 = __float2bfloat16(hn0), hb1 = __float2bfloat16(hn1);
            uint32_t pk = ((uint32_t)(*(uint16_t*)&hb1) << 16) | (uint32_t)(*(uint16_t*)&hb0);

            float pv = hn0 * wle + hn1 * wlo;
            pv += __shfl_xor(pv, 4);
            pv += __shfl_xor(pv, 8);

            // publish h1(s) + op(s), both tagged. NO drain.
            st64((unsigned long long*)
                 (h1t + (size_t)(((s & 3) * NC + c) * 8 + (j - 8)) * 2048
                      + row * 128 + (wave * 4 + q_l) * 8),
                 (unsigned long long)pk | ((unsigned long long)(uint32_t)(s + 1) << 32));
            if ((lane & 12) == 0)
                st64(op + (size_t)(((s & 15) * NC + c) * 16 + row) * 32 + (j - 8) * 4 + wave,
                     (unsigned long long)__float_as_uint(pv)
                     | ((unsigned long long)(uint32_t)(s + 1) << 32));
            barrier_raw();
        }
        // final flag: op(TT-1)/h1(TT-1) stores issued (program order + barrier)
        if (tid == 0) st32(myflag, (uint32_t)(TT + 1));
    }
}

extern "C" void kernel_launch(void* const* d_in, const int* in_sizes, int n_in,
                              void* d_out, int out_size, void* d_ws, size_t ws_size,
                              hipStream_t stream)
{
    const float* x    = (const float*)d_in[0];
    const float* Wih0 = (const float*)d_in[1];
    const float* Whh0 = (const float*)d_in[2];
    const float* bih0 = (const float*)d_in[3];
    const float* bhh0 = (const float*)d_in[4];
    const float* Wih1 = (const float*)d_in[5];
    const float* Whh1 = (const float*)d_in[6];
    const float* bih1 = (const float*)d_in[7];
    const float* bhh1 = (const float*)d_in[8];
    const float* Wlin = (const float*)d_in[9];
    const float* blin = (const float*)d_in[10];
    float* out = (float*)d_out;
    char* ws   = (char*)d_ws;

    // 256 blocks x 256 threads, 1 block/CU -> all co-resident (spin-safe).
    lstm_kernel<<<dim3(256), dim3(256), 0, stream>>>(
        x, Wih0, Whh0, bih0, bhh0, Wih1, Whh1, bih1, bhh1, Wlin, blin, out, ws);
}